// Round 7
// baseline (109.727 us; speedup 1.0000x reference)
//
#include <hip/hip_runtime.h>

// MemoryEfficientAttention: B=2,H=16,S=4096,D=128, CHUNK=1024.
// R7: ZERO LDS, ZERO barriers. K/V pre-converted (bf16) by prep into
// fragment-coalesced layouts; main kernel reads MFMA fragments directly
// from L2-resident ws (512KB/bh, 2MB/XCD). 12 independent waves/CU hide
// L2 latency; no lockstep. No-max softmax, diag parity half-skip.

typedef __attribute__((ext_vector_type(8))) short bfrag_t;   // 8 bf16
typedef __attribute__((ext_vector_type(16))) float f32x16;
typedef unsigned short u16;
typedef unsigned int   u32;

#define SEQ     4096
#define SCHUNK  1024
#define HD      128
#define NTILE   16
#define TILE_E  8192

__device__ __forceinline__ u16 f2bf(float f) {
    union { float f; unsigned u; } x; x.f = f;
    unsigned r = x.u + 0x7fffu + ((x.u >> 16) & 1u);   // RNE
    return (u16)(r >> 16);
}

// ---------------- prep: f32 -> bf16 into fragment-coalesced layouts ----------
// kws tile: elem K[j][s*8+e] at (s*64 + j)*8 + e        (s=0..15, j=0..63)
//   -> QK kf load (lane c31,hi; ks): two contiguous 512B runs per instr.
// vws tile: elem V[sv*8+jj][d] at (sv*128 + d)*8 + jj   (sv=0..7, d=0..127)
//   -> PV vf load (lane c31,hi; dg,jsl): two contiguous 512B runs per instr.
__global__ __launch_bounds__(256)
void mea_prep(const float* __restrict__ kg, const float* __restrict__ vg,
              u16* __restrict__ wsK, u16* __restrict__ wsV)
{
    const int tid  = threadIdx.x;
    const int tile = blockIdx.x;            // 512 = 32 bh x 16 kt
    const int bh = tile >> 4, kt = tile & 15;
    const long gsrc = (long)bh * SEQ * HD + (long)kt * 64 * HD;
    const long gdst = (long)tile * TILE_E;

    // K: thread (s = oid>>6, j = oid&63) reads K[j][s*8..+8], writes coalesced
#pragma unroll
    for (int i = 0; i < 4; ++i) {
        int oid = i * 256 + tid;
        int s = oid >> 6, j = oid & 63;
        const float* kp = kg + gsrc + j * HD + s * 8;
        float4 a = *(const float4*)kp;
        float4 b = *(const float4*)(kp + 4);
        bfrag_t f;
        f[0]=f2bf(a.x); f[1]=f2bf(a.y); f[2]=f2bf(a.z); f[3]=f2bf(a.w);
        f[4]=f2bf(b.x); f[5]=f2bf(b.y); f[6]=f2bf(b.z); f[7]=f2bf(b.w);
        *(bfrag_t*)(wsK + gdst + (s * 64 + j) * 8) = f;
    }
    // V: thread (sv = oid>>7, d = oid&127) reads V[sv*8+jj][d], writes coalesced
#pragma unroll
    for (int i = 0; i < 4; ++i) {
        int oid = i * 256 + tid;
        int sv = oid >> 7, d = oid & 127;
        const float* vp = vg + gsrc + sv * 8 * HD + d;
        bfrag_t f;
#pragma unroll
        for (int jj = 0; jj < 8; ++jj) f[jj] = f2bf(vp[jj * HD]);
        *(bfrag_t*)(wsV + gdst + (sv * 128 + d) * 8) = f;
    }
}

__device__ __forceinline__ float tsum16(const f32x16& p) {
    float a0 = (p[0] + p[1]) + (p[2] + p[3]);
    float a1 = (p[4] + p[5]) + (p[6] + p[7]);
    float a2 = (p[8] + p[9]) + (p[10] + p[11]);
    float a3 = (p[12] + p[13]) + (p[14] + p[15]);
    return (a0 + a1) + (a2 + a3);
}

// ---------------- main attention kernel (no LDS, no barriers) ----------------
__global__ __launch_bounds__(256, 3)
void mea_main(const float* __restrict__ qg, const u16* __restrict__ wsK,
              const u16* __restrict__ wsV, float* __restrict__ og)
{
    const int tid  = threadIdx.x;
    const int lane = tid & 63;
    const int wv   = tid >> 6;       // chunk 0..3
    const int c31  = lane & 31;
    const int hi   = lane >> 5;

    // XCD-aware: 4 bh per XCD; heavy q-tiles first within each XCD
    const int x   = blockIdx.x & 7;
    const int idx = blockIdx.x >> 3;          // 0..127
    const int qt  = 31 - (idx >> 2);          // 32-row q-tile, heavy first
    const int bh  = x * 4 + (idx & 3);

    const long rowbase = (long)bh * SEQ + (long)wv * SCHUNK + (long)qt * 32;
    const u16* Kb = wsK + (long)bh * NTILE * TILE_E;
    const u16* Vb = wsV + (long)bh * NTILE * TILE_E;

    // ---- Q fragments (B-op: n=q=c31, k=d=ks*16+hi*8+e); fold scale*log2e
    bfrag_t qf[8];
    {
        const float qs = 0.12751723f;   // rsqrt(128) * log2(e)
        const float* qp = qg + (rowbase + c31) * HD + hi * 8;
#pragma unroll
        for (int ks = 0; ks < 8; ++ks) {
            float4 a = *(const float4*)(qp + ks * 16);
            float4 b = *(const float4*)(qp + ks * 16 + 4);
            bfrag_t f;
            f[0]=f2bf(a.x*qs); f[1]=f2bf(a.y*qs); f[2]=f2bf(a.z*qs); f[3]=f2bf(a.w*qs);
            f[4]=f2bf(b.x*qs); f[5]=f2bf(b.y*qs); f[6]=f2bf(b.z*qs); f[7]=f2bf(b.w*qs);
            qf[ks] = f;
        }
    }

    f32x16 oacc[4];                  // O^T[d][q]: lane=q-col, 16 d-rows per dgrp
#pragma unroll
    for (int d = 0; d < 4; ++d)
#pragma unroll
        for (int i = 0; i < 16; ++i) oacc[d][i] = 0.f;

    float lsum = 0.f;                // this lane's half of the denominator
    const int nt  = (qt >> 1) + 1;   // causal K-tile count
    const int par = qt & 1;          // 0: diag masks g0 (skip g1); 1: diag masks g1

    // per-lane fragment offsets (loop-invariant parts)
    const int kofs = (hi * 64 + c31) * 8;        // + ks*1024 per k-slice
    const int vofs = (hi * 128 + c31) * 8;       // + jsl*2048 + dg*256

    for (int kt = 0; kt < nt; ++kt) {
        const u16* Kt = Kb + (long)kt * TILE_E;
        const u16* Vt = Vb + (long)kt * TILE_E;
        const bool diag = (kt == nt - 1);
        const bool do1  = !(diag && par == 0);   // even-qt diagonal: skip g1
        bfrag_t pfrag[4];

        // ======== g = 0 (K rows 0..31) ========
        {
            bfrag_t kf[8];
#pragma unroll
            for (int ks = 0; ks < 8; ++ks)
                kf[ks] = *(const bfrag_t*)(Kt + ks * 1024 + kofs);
            f32x16 s;
#pragma unroll
            for (int i = 0; i < 16; ++i) s[i] = 0.f;
#pragma unroll
            for (int ks = 0; ks < 8; ++ks)
                s = __builtin_amdgcn_mfma_f32_32x32x16_bf16(kf[ks], qf[ks], s, 0, 0, 0);
            if (diag && par == 0) {   // triangular mask: crow > c31
#pragma unroll
                for (int r = 0; r < 16; ++r) {
                    int crow = (r & 3) + 8 * (r >> 2) + 4 * hi;
                    if (crow > c31) s[r] = -1e30f;
                }
            }
#pragma unroll
            for (int r = 0; r < 16; ++r) s[r] = exp2f(s[r]);
            lsum += tsum16(s);
            u32 W[8];
#pragma unroll
            for (int t2 = 0; t2 < 8; ++t2)
                asm("v_cvt_pk_bf16_f32 %0, %1, %2"
                    : "=v"(W[t2]) : "v"(s[2 * t2]), "v"(s[2 * t2 + 1]));
#pragma unroll
            for (int u2 = 0; u2 < 2; ++u2) {
                u32 x0 = W[4 * u2 + 0], y0 = W[4 * u2 + 2];
                u32 x1 = W[4 * u2 + 1], y1 = W[4 * u2 + 3];
                asm("v_permlane32_swap_b32 %0, %1" : "+v"(x0), "+v"(y0));
                asm("v_permlane32_swap_b32 %0, %1" : "+v"(x1), "+v"(y1));
                union { u32 w[4]; bfrag_t f; } cvt;
                cvt.w[0] = x0; cvt.w[1] = x1; cvt.w[2] = y0; cvt.w[3] = y1;
                pfrag[u2] = cvt.f;
            }
        }
        // ======== g = 1 (K rows 32..63) ========
        if (do1) {
            bfrag_t kf[8];
#pragma unroll
            for (int ks = 0; ks < 8; ++ks)
                kf[ks] = *(const bfrag_t*)(Kt + ks * 1024 + 256 + kofs);
            f32x16 s;
#pragma unroll
            for (int i = 0; i < 16; ++i) s[i] = 0.f;
#pragma unroll
            for (int ks = 0; ks < 8; ++ks)
                s = __builtin_amdgcn_mfma_f32_32x32x16_bf16(kf[ks], qf[ks], s, 0, 0, 0);
            if (diag) {               // par==1: triangular mask on g1
#pragma unroll
                for (int r = 0; r < 16; ++r) {
                    int crow = (r & 3) + 8 * (r >> 2) + 4 * hi;
                    if (crow > c31) s[r] = -1e30f;
                }
            }
#pragma unroll
            for (int r = 0; r < 16; ++r) s[r] = exp2f(s[r]);
            lsum += tsum16(s);
            u32 W[8];
#pragma unroll
            for (int t2 = 0; t2 < 8; ++t2)
                asm("v_cvt_pk_bf16_f32 %0, %1, %2"
                    : "=v"(W[t2]) : "v"(s[2 * t2]), "v"(s[2 * t2 + 1]));
#pragma unroll
            for (int u2 = 0; u2 < 2; ++u2) {
                u32 x0 = W[4 * u2 + 0], y0 = W[4 * u2 + 2];
                u32 x1 = W[4 * u2 + 1], y1 = W[4 * u2 + 3];
                asm("v_permlane32_swap_b32 %0, %1" : "+v"(x0), "+v"(y0));
                asm("v_permlane32_swap_b32 %0, %1" : "+v"(x1), "+v"(y1));
                union { u32 w[4]; bfrag_t f; } cvt;
                cvt.w[0] = x0; cvt.w[1] = x1; cvt.w[2] = y0; cvt.w[3] = y1;
                pfrag[2 + u2] = cvt.f;
            }
        }

        // ---- O^T += V^T * P^T (vf direct from L2; dg chains independent)
#pragma unroll
        for (int dg = 0; dg < 4; ++dg) {
            const u16* vbase = Vt + dg * 256 + vofs;
            bfrag_t vf0 = *(const bfrag_t*)(vbase);
            bfrag_t vf1 = *(const bfrag_t*)(vbase + 2048);
            oacc[dg] = __builtin_amdgcn_mfma_f32_32x32x16_bf16(vf0, pfrag[0], oacc[dg], 0, 0, 0);
            oacc[dg] = __builtin_amdgcn_mfma_f32_32x32x16_bf16(vf1, pfrag[1], oacc[dg], 0, 0, 0);
            if (do1) {
                bfrag_t vf2 = *(const bfrag_t*)(vbase + 4096);
                bfrag_t vf3 = *(const bfrag_t*)(vbase + 6144);
                oacc[dg] = __builtin_amdgcn_mfma_f32_32x32x16_bf16(vf2, pfrag[2], oacc[dg], 0, 0, 0);
                oacc[dg] = __builtin_amdgcn_mfma_f32_32x32x16_bf16(vf3, pfrag[3], oacc[dg], 0, 0, 0);
            }
        }
    }

    // ---- epilogue: ONE cross-half reduction completes the denominator
    lsum += __shfl_xor(lsum, 32);
    float inv = 1.f / lsum;
#pragma unroll
    for (int dg = 0; dg < 4; ++dg) {
#pragma unroll
        for (int rq = 0; rq < 4; ++rq) {
            float4 v;
            v.x = oacc[dg][rq * 4 + 0] * inv;
            v.y = oacc[dg][rq * 4 + 1] * inv;
            v.z = oacc[dg][rq * 4 + 2] * inv;
            v.w = oacc[dg][rq * 4 + 3] * inv;
            *(float4*)(og + (rowbase + c31) * HD + dg * 32 + rq * 8 + hi * 4) = v;
        }
    }
}

extern "C" void kernel_launch(void* const* d_in, const int* in_sizes, int n_in,
                              void* d_out, int out_size, void* d_ws, size_t ws_size,
                              hipStream_t stream)
{
    (void)in_sizes; (void)n_in; (void)out_size; (void)ws_size;
    const float* q = (const float*)d_in[0];
    const float* k = (const float*)d_in[1];
    const float* v = (const float*)d_in[2];
    float* o = (float*)d_out;
    u16* wsK = (u16*)d_ws;
    u16* wsV = wsK + (size_t)32 * NTILE * TILE_E;   // 8MB each
    mea_prep<<<dim3(512),  dim3(256), 0, stream>>>(k, v, wsK, wsV);
    // grid: 8 XCD x (32 qt heavy-first x 4 bh)
    mea_main<<<dim3(1024), dim3(256), 0, stream>>>(q, wsK, wsV, o);
}

// Round 8
// 82.221 us; speedup vs baseline: 1.3345x; 1.3345x over previous
//
#include <hip/hip_runtime.h>

// MemoryEfficientAttention: B=2,H=16,S=4096,D=128, CHUNK=1024.
// R8 = R6 + counted-vmcnt mid-tile barrier (K-prefetch stays in flight
// across the PV barrier; T4) + QK split into 2 independent MFMA chains.
// 256-thr blocks, 3 blocks/CU, LDS 48KB (K dbuf + V single), no-max
// softmax, diag parity half-skip, pre-swizzled bf16 ws, gll16 DMA.

typedef __attribute__((ext_vector_type(8))) short bfrag_t;   // 8 bf16
typedef __attribute__((ext_vector_type(16))) float f32x16;
typedef unsigned short u16;
typedef unsigned int   u32;

#define SEQ     4096
#define SCHUNK  1024
#define HD      128
#define NTILE   16
#define TILE_E  8192

__device__ __forceinline__ u16 f2bf(float f) {
    union { float f; unsigned u; } x; x.f = f;
    unsigned r = x.u + 0x7fffu + ((x.u >> 16) & 1u);   // RNE
    return (u16)(r >> 16);
}

// ---------------- prep: f32 -> bf16, transpose V, bake LDS swizzle ----------------
// K tile: elem K[j][s*8+e] at j*128 + ((s ^ (j&15))*8) + e          (s=0..15)
// V^T tile: elem V[jo*8+jj][d] at d2*128 + (((jo + 8*(d&1)) ^ (d2&15))*8) + jj, d2=d>>1
__global__ __launch_bounds__(256)
void mea_prep(const float* __restrict__ kg, const float* __restrict__ vg,
              u16* __restrict__ wsK, u16* __restrict__ wsV)
{
    const int tid  = threadIdx.x;
    const int tile = blockIdx.x;            // 512 = 32 bh x 16 kt
    const int bh = tile >> 4, kt = tile & 15;
    const long gsrc = (long)bh * SEQ * HD + (long)kt * 64 * HD;
    const long gdst = (long)tile * TILE_E;

#pragma unroll
    for (int i = 0; i < 4; ++i) {
        int oid = i * 256 + tid;
        int j = oid >> 4, s = oid & 15;
        const float* kp = kg + gsrc + j * HD + s * 8;
        float4 a = *(const float4*)kp;
        float4 b = *(const float4*)(kp + 4);
        bfrag_t f;
        f[0]=f2bf(a.x); f[1]=f2bf(a.y); f[2]=f2bf(a.z); f[3]=f2bf(a.w);
        f[4]=f2bf(b.x); f[5]=f2bf(b.y); f[6]=f2bf(b.z); f[7]=f2bf(b.w);
        *(bfrag_t*)(wsK + gdst + j * 128 + ((s ^ (j & 15)) * 8)) = f;
    }
#pragma unroll
    for (int i = 0; i < 4; ++i) {
        int oid = i * 256 + tid;
        int jo = oid >> 7, d = oid & 127;
        const float* vp = vg + gsrc + jo * 8 * HD + d;
        bfrag_t f;
#pragma unroll
        for (int jj = 0; jj < 8; ++jj) f[jj] = f2bf(vp[jj * HD]);
        int d2 = d >> 1;
        int S  = (jo + ((d & 1) << 3)) ^ (d2 & 15);
        *(bfrag_t*)(wsV + gdst + d2 * 128 + S * 8) = f;
    }
}

__device__ __forceinline__ void gll16(const u16* g, u16* l) {
    __builtin_amdgcn_global_load_lds((const __attribute__((address_space(1))) u32*)g,
                                     (__attribute__((address_space(3))) u32*)l, 16, 0, 0);
}

__device__ __forceinline__ float tsum16(const f32x16& p) {
    float a0 = (p[0] + p[1]) + (p[2] + p[3]);
    float a1 = (p[4] + p[5]) + (p[6] + p[7]);
    float a2 = (p[8] + p[9]) + (p[10] + p[11]);
    float a3 = (p[12] + p[13]) + (p[14] + p[15]);
    return (a0 + a1) + (a2 + a3);
}

// ---------------- main attention kernel ----------------
__global__ __launch_bounds__(256, 3)
void mea_main(const float* __restrict__ qg, const u16* __restrict__ wsK,
              const u16* __restrict__ wsV, float* __restrict__ og)
{
    __shared__ __align__(16) u16 K_s[2][TILE_E];   // 16KB x2, double-buffered
    __shared__ __align__(16) u16 V_s[TILE_E];      // 16KB, single-buffered

    const int tid  = threadIdx.x;
    const int lane = tid & 63;
    const int wv   = tid >> 6;       // chunk 0..3
    const int c31  = lane & 31;
    const int hi   = lane >> 5;

    // XCD-aware: 4 bh per XCD; heavy q-tiles first within each XCD
    const int x   = blockIdx.x & 7;
    const int idx = blockIdx.x >> 3;          // 0..127
    const int qt  = 31 - (idx >> 2);          // 32-row q-tile, heavy first
    const int bh  = x * 4 + (idx & 3);

    const long rowbase = (long)bh * SEQ + (long)wv * SCHUNK + (long)qt * 32;
    const u16* Kb = wsK + (long)bh * NTILE * TILE_E;
    const u16* Vb = wsV + (long)bh * NTILE * TILE_E;

    // ---- Q fragments (B-op: n=q=c31, k=d=ks*16+hi*8+e); fold scale*log2e
    bfrag_t qf[8];
    {
        const float qs = 0.12751723f;   // rsqrt(128) * log2(e)
        const float* qp = qg + (rowbase + c31) * HD + hi * 8;
#pragma unroll
        for (int ks = 0; ks < 8; ++ks) {
            float4 a = *(const float4*)(qp + ks * 16);
            float4 b = *(const float4*)(qp + ks * 16 + 4);
            bfrag_t f;
            f[0]=f2bf(a.x*qs); f[1]=f2bf(a.y*qs); f[2]=f2bf(a.z*qs); f[3]=f2bf(a.w*qs);
            f[4]=f2bf(b.x*qs); f[5]=f2bf(b.y*qs); f[6]=f2bf(b.z*qs); f[7]=f2bf(b.w*qs);
            qf[ks] = f;
        }
    }

    f32x16 oacc[4];                  // O^T[d][q]: lane=q-col, 16 d-rows per dgrp
#pragma unroll
    for (int d = 0; d < 4; ++d)
#pragma unroll
        for (int i = 0; i < 16; ++i) oacc[d][i] = 0.f;

    float lsum = 0.f;                // this lane's half of the denominator
    const int nt   = (qt >> 1) + 1;        // causal K-tile count
    const int par  = qt & 1;               // 0: diag masks g0 (skip g1); 1: diag masks g1
    const int so   = wv * 2048 + lane * 8; // wave's global-src slice (u16 elems)
    const int ldsb = wv * 2048;            // wave-uniform LDS dest base

    // prologue: DMA K tile 0 -> Kbuf0
#pragma unroll
    for (int c = 0; c < 4; ++c)
        gll16(Kb + so + c * 512, &K_s[0][ldsb + c * 512]);

    int cur = 0;
    for (int kt = 0; kt < nt; ++kt) {
        __syncthreads();   // vmcnt(0): Kbuf[cur] (and anything older) landed everywhere

        // Issue V(kt) FIRST (oldest -> drains at vmcnt(4)), then K(kt+1) prefetch
#pragma unroll
        for (int c = 0; c < 4; ++c)
            gll16(Vb + (long)kt * TILE_E + so + c * 512, &V_s[ldsb + c * 512]);
        const bool pre = (kt + 1 < nt);
        if (pre) {
            const long tb = (long)(kt + 1) * TILE_E;
#pragma unroll
            for (int c = 0; c < 4; ++c)
                gll16(Kb + tb + so + c * 512, &K_s[cur ^ 1][ldsb + c * 512]);
        }

        const bool diag = (kt == nt - 1);
        const bool do1  = !(diag && par == 0);   // even-qt diagonal: skip g1
        bfrag_t pfrag[4];

        // ======== g = 0 (two independent 4-deep MFMA chains) ========
        {
            f32x16 s, sb;
#pragma unroll
            for (int i = 0; i < 16; ++i) { s[i] = 0.f; sb[i] = 0.f; }
            const u16* krow = &K_s[cur][c31 * 128];
#pragma unroll
            for (int ks = 0; ks < 4; ++ks) {
                int slot = (ks * 2 + hi) ^ (c31 & 15);
                bfrag_t kf = *(const bfrag_t*)(krow + slot * 8);
                s = __builtin_amdgcn_mfma_f32_32x32x16_bf16(kf, qf[ks], s, 0, 0, 0);
            }
#pragma unroll
            for (int ks = 4; ks < 8; ++ks) {
                int slot = (ks * 2 + hi) ^ (c31 & 15);
                bfrag_t kf = *(const bfrag_t*)(krow + slot * 8);
                sb = __builtin_amdgcn_mfma_f32_32x32x16_bf16(kf, qf[ks], sb, 0, 0, 0);
            }
#pragma unroll
            for (int i = 0; i < 16; ++i) s[i] += sb[i];
            if (diag && par == 0) {   // triangular mask: crow > c31
#pragma unroll
                for (int r = 0; r < 16; ++r) {
                    int crow = (r & 3) + 8 * (r >> 2) + 4 * hi;
                    if (crow > c31) s[r] = -1e30f;
                }
            }
#pragma unroll
            for (int r = 0; r < 16; ++r) s[r] = exp2f(s[r]);
            lsum += tsum16(s);
            u32 W[8];
#pragma unroll
            for (int t2 = 0; t2 < 8; ++t2)
                asm("v_cvt_pk_bf16_f32 %0, %1, %2"
                    : "=v"(W[t2]) : "v"(s[2 * t2]), "v"(s[2 * t2 + 1]));
#pragma unroll
            for (int u2 = 0; u2 < 2; ++u2) {
                u32 x0 = W[4 * u2 + 0], y0 = W[4 * u2 + 2];
                u32 x1 = W[4 * u2 + 1], y1 = W[4 * u2 + 3];
                asm("v_permlane32_swap_b32 %0, %1" : "+v"(x0), "+v"(y0));
                asm("v_permlane32_swap_b32 %0, %1" : "+v"(x1), "+v"(y1));
                union { u32 w[4]; bfrag_t f; } cvt;
                cvt.w[0] = x0; cvt.w[1] = x1; cvt.w[2] = y0; cvt.w[3] = y1;
                pfrag[u2] = cvt.f;
            }
        }
        // ======== g = 1 ========
        if (do1) {
            f32x16 s, sb;
#pragma unroll
            for (int i = 0; i < 16; ++i) { s[i] = 0.f; sb[i] = 0.f; }
            const u16* krow = &K_s[cur][(32 + c31) * 128];
#pragma unroll
            for (int ks = 0; ks < 4; ++ks) {
                int slot = (ks * 2 + hi) ^ (c31 & 15);
                bfrag_t kf = *(const bfrag_t*)(krow + slot * 8);
                s = __builtin_amdgcn_mfma_f32_32x32x16_bf16(kf, qf[ks], s, 0, 0, 0);
            }
#pragma unroll
            for (int ks = 4; ks < 8; ++ks) {
                int slot = (ks * 2 + hi) ^ (c31 & 15);
                bfrag_t kf = *(const bfrag_t*)(krow + slot * 8);
                sb = __builtin_amdgcn_mfma_f32_32x32x16_bf16(kf, qf[ks], sb, 0, 0, 0);
            }
#pragma unroll
            for (int i = 0; i < 16; ++i) s[i] += sb[i];
            if (diag) {               // par==1: triangular mask on g1
#pragma unroll
                for (int r = 0; r < 16; ++r) {
                    int crow = (r & 3) + 8 * (r >> 2) + 4 * hi;
                    if (crow > c31) s[r] = -1e30f;
                }
            }
#pragma unroll
            for (int r = 0; r < 16; ++r) s[r] = exp2f(s[r]);
            lsum += tsum16(s);
            u32 W[8];
#pragma unroll
            for (int t2 = 0; t2 < 8; ++t2)
                asm("v_cvt_pk_bf16_f32 %0, %1, %2"
                    : "=v"(W[t2]) : "v"(s[2 * t2]), "v"(s[2 * t2 + 1]));
#pragma unroll
            for (int u2 = 0; u2 < 2; ++u2) {
                u32 x0 = W[4 * u2 + 0], y0 = W[4 * u2 + 2];
                u32 x1 = W[4 * u2 + 1], y1 = W[4 * u2 + 3];
                asm("v_permlane32_swap_b32 %0, %1" : "+v"(x0), "+v"(y0));
                asm("v_permlane32_swap_b32 %0, %1" : "+v"(x1), "+v"(y1));
                union { u32 w[4]; bfrag_t f; } cvt;
                cvt.w[0] = x0; cvt.w[1] = x1; cvt.w[2] = y0; cvt.w[3] = y1;
                pfrag[2 + u2] = cvt.f;
            }
        }

        // ---- counted-vmcnt barrier: wait V's 4 loads only; K-prefetch (4)
        //      stays in flight across the barrier, drains at next __syncthreads.
        if (pre) asm volatile("s_waitcnt vmcnt(4)\n\ts_barrier" ::: "memory");
        else     asm volatile("s_waitcnt vmcnt(0)\n\ts_barrier" ::: "memory");

        // ---- O^T += V^T * P^T
#pragma unroll
        for (int dg = 0; dg < 4; ++dg) {
            const int d  = dg * 32 + c31;
            const int d2 = d >> 1;
            const u16* vrow = &V_s[d2 * 128];
#pragma unroll
            for (int jsl = 0; jsl < 2; ++jsl) {
                int S = ((jsl * 2 + hi) + ((d & 1) << 3)) ^ (d2 & 15);
                bfrag_t vf = *(const bfrag_t*)(vrow + S * 8);
                oacc[dg] = __builtin_amdgcn_mfma_f32_32x32x16_bf16(vf, pfrag[jsl], oacc[dg], 0, 0, 0);
            }
        }
        if (do1) {
#pragma unroll
            for (int dg = 0; dg < 4; ++dg) {
                const int d  = dg * 32 + c31;
                const int d2 = d >> 1;
                const u16* vrow = &V_s[d2 * 128];
#pragma unroll
                for (int jsl = 2; jsl < 4; ++jsl) {
                    int S = ((jsl * 2 + hi) + ((d & 1) << 3)) ^ (d2 & 15);
                    bfrag_t vf = *(const bfrag_t*)(vrow + S * 8);
                    oacc[dg] = __builtin_amdgcn_mfma_f32_32x32x16_bf16(vf, pfrag[jsl], oacc[dg], 0, 0, 0);
                }
            }
        }

        cur ^= 1;
    }

    // ---- epilogue: ONE cross-half reduction completes the denominator
    lsum += __shfl_xor(lsum, 32);
    float inv = 1.f / lsum;
#pragma unroll
    for (int dg = 0; dg < 4; ++dg) {
#pragma unroll
        for (int rq = 0; rq < 4; ++rq) {
            float4 v;
            v.x = oacc[dg][rq * 4 + 0] * inv;
            v.y = oacc[dg][rq * 4 + 1] * inv;
            v.z = oacc[dg][rq * 4 + 2] * inv;
            v.w = oacc[dg][rq * 4 + 3] * inv;
            *(float4*)(og + (rowbase + c31) * HD + dg * 32 + rq * 8 + hi * 4) = v;
        }
    }
}

extern "C" void kernel_launch(void* const* d_in, const int* in_sizes, int n_in,
                              void* d_out, int out_size, void* d_ws, size_t ws_size,
                              hipStream_t stream)
{
    (void)in_sizes; (void)n_in; (void)out_size; (void)ws_size;
    const float* q = (const float*)d_in[0];
    const float* k = (const float*)d_in[1];
    const float* v = (const float*)d_in[2];
    float* o = (float*)d_out;
    u16* wsK = (u16*)d_ws;
    u16* wsV = wsK + (size_t)32 * NTILE * TILE_E;   // 8MB each
    mea_prep<<<dim3(512),  dim3(256), 0, stream>>>(k, v, wsK, wsV);
    // grid: 8 XCD x (32 qt heavy-first x 4 bh); 3 blocks/CU
    mea_main<<<dim3(1024), dim3(256), 0, stream>>>(q, wsK, wsV, o);
}

// Round 9
// 79.769 us; speedup vs baseline: 1.3756x; 1.0307x over previous
//
#include <hip/hip_runtime.h>

// MemoryEfficientAttention: B=2,H=16,S=4096,D=128, CHUNK=1024.
// R9 = R6 with V double-buffered too: 64KB LDS, ONE barrier per tile
// (straight-line QK->softmax->PV between joins), 2 blocks/CU.
// No-max softmax, diag parity half-skip, pre-swizzled bf16 ws, gll16 DMA.

typedef __attribute__((ext_vector_type(8))) short bfrag_t;   // 8 bf16
typedef __attribute__((ext_vector_type(16))) float f32x16;
typedef unsigned short u16;
typedef unsigned int   u32;

#define SEQ     4096
#define SCHUNK  1024
#define HD      128
#define NTILE   16
#define TILE_E  8192

__device__ __forceinline__ u16 f2bf(float f) {
    union { float f; unsigned u; } x; x.f = f;
    unsigned r = x.u + 0x7fffu + ((x.u >> 16) & 1u);   // RNE
    return (u16)(r >> 16);
}

// ---------------- prep: f32 -> bf16, transpose V, bake LDS swizzle ----------------
// K tile: elem K[j][s*8+e] at j*128 + ((s ^ (j&15))*8) + e          (s=0..15)
// V^T tile: elem V[jo*8+jj][d] at d2*128 + (((jo + 8*(d&1)) ^ (d2&15))*8) + jj, d2=d>>1
__global__ __launch_bounds__(256)
void mea_prep(const float* __restrict__ kg, const float* __restrict__ vg,
              u16* __restrict__ wsK, u16* __restrict__ wsV)
{
    const int tid  = threadIdx.x;
    const int tile = blockIdx.x;            // 512 = 32 bh x 16 kt
    const int bh = tile >> 4, kt = tile & 15;
    const long gsrc = (long)bh * SEQ * HD + (long)kt * 64 * HD;
    const long gdst = (long)tile * TILE_E;

#pragma unroll
    for (int i = 0; i < 4; ++i) {
        int oid = i * 256 + tid;
        int j = oid >> 4, s = oid & 15;
        const float* kp = kg + gsrc + j * HD + s * 8;
        float4 a = *(const float4*)kp;
        float4 b = *(const float4*)(kp + 4);
        bfrag_t f;
        f[0]=f2bf(a.x); f[1]=f2bf(a.y); f[2]=f2bf(a.z); f[3]=f2bf(a.w);
        f[4]=f2bf(b.x); f[5]=f2bf(b.y); f[6]=f2bf(b.z); f[7]=f2bf(b.w);
        *(bfrag_t*)(wsK + gdst + j * 128 + ((s ^ (j & 15)) * 8)) = f;
    }
#pragma unroll
    for (int i = 0; i < 4; ++i) {
        int oid = i * 256 + tid;
        int jo = oid >> 7, d = oid & 127;
        const float* vp = vg + gsrc + jo * 8 * HD + d;
        bfrag_t f;
#pragma unroll
        for (int jj = 0; jj < 8; ++jj) f[jj] = f2bf(vp[jj * HD]);
        int d2 = d >> 1;
        int S  = (jo + ((d & 1) << 3)) ^ (d2 & 15);
        *(bfrag_t*)(wsV + gdst + d2 * 128 + S * 8) = f;
    }
}

__device__ __forceinline__ void gll16(const u16* g, u16* l) {
    __builtin_amdgcn_global_load_lds((const __attribute__((address_space(1))) u32*)g,
                                     (__attribute__((address_space(3))) u32*)l, 16, 0, 0);
}

__device__ __forceinline__ float tsum16(const f32x16& p) {
    float a0 = (p[0] + p[1]) + (p[2] + p[3]);
    float a1 = (p[4] + p[5]) + (p[6] + p[7]);
    float a2 = (p[8] + p[9]) + (p[10] + p[11]);
    float a3 = (p[12] + p[13]) + (p[14] + p[15]);
    return (a0 + a1) + (a2 + a3);
}

// ---------------- main attention kernel ----------------
__global__ __launch_bounds__(256, 2)
void mea_main(const float* __restrict__ qg, const u16* __restrict__ wsK,
              const u16* __restrict__ wsV, float* __restrict__ og)
{
    __shared__ __align__(16) u16 K_s[2][TILE_E];   // 16KB x2
    __shared__ __align__(16) u16 V_s[2][TILE_E];   // 16KB x2

    const int tid  = threadIdx.x;
    const int lane = tid & 63;
    const int wv   = tid >> 6;       // chunk 0..3
    const int c31  = lane & 31;
    const int hi   = lane >> 5;

    // XCD-aware: 4 bh per XCD; heavy q-tiles first within each XCD
    const int x   = blockIdx.x & 7;
    const int idx = blockIdx.x >> 3;          // 0..127
    const int qt  = 31 - (idx >> 2);          // 32-row q-tile, heavy first
    const int bh  = x * 4 + (idx & 3);

    const long rowbase = (long)bh * SEQ + (long)wv * SCHUNK + (long)qt * 32;
    const u16* Kb = wsK + (long)bh * NTILE * TILE_E;
    const u16* Vb = wsV + (long)bh * NTILE * TILE_E;

    // ---- Q fragments (B-op: n=q=c31, k=d=ks*16+hi*8+e); fold scale*log2e
    bfrag_t qf[8];
    {
        const float qs = 0.12751723f;   // rsqrt(128) * log2(e)
        const float* qp = qg + (rowbase + c31) * HD + hi * 8;
#pragma unroll
        for (int ks = 0; ks < 8; ++ks) {
            float4 a = *(const float4*)(qp + ks * 16);
            float4 b = *(const float4*)(qp + ks * 16 + 4);
            bfrag_t f;
            f[0]=f2bf(a.x*qs); f[1]=f2bf(a.y*qs); f[2]=f2bf(a.z*qs); f[3]=f2bf(a.w*qs);
            f[4]=f2bf(b.x*qs); f[5]=f2bf(b.y*qs); f[6]=f2bf(b.z*qs); f[7]=f2bf(b.w*qs);
            qf[ks] = f;
        }
    }

    f32x16 oacc[4];                  // O^T[d][q]: lane=q-col, 16 d-rows per dgrp
#pragma unroll
    for (int d = 0; d < 4; ++d)
#pragma unroll
        for (int i = 0; i < 16; ++i) oacc[d][i] = 0.f;

    float lsum = 0.f;                // this lane's half of the denominator
    const int nt   = (qt >> 1) + 1;        // causal K-tile count
    const int par  = qt & 1;               // 0: diag masks g0 (skip g1); 1: diag masks g1
    const int so   = wv * 2048 + lane * 8; // wave's global-src slice (u16 elems)
    const int ldsb = wv * 2048;            // wave-uniform LDS dest base

    // prologue: DMA K(0), V(0) -> buf0
#pragma unroll
    for (int c = 0; c < 4; ++c) {
        gll16(Kb + so + c * 512, &K_s[0][ldsb + c * 512]);
        gll16(Vb + so + c * 512, &V_s[0][ldsb + c * 512]);
    }

    int cur = 0;
    for (int kt = 0; kt < nt; ++kt) {
        __syncthreads();   // vmcnt(0): K(kt),V(kt) landed everywhere; bufs ^1 free

        if (kt + 1 < nt) {   // prefetch kt+1 into the other buffers (full tile to land)
            const long tb = (long)(kt + 1) * TILE_E;
#pragma unroll
            for (int c = 0; c < 4; ++c) {
                gll16(Kb + tb + so + c * 512, &K_s[cur ^ 1][ldsb + c * 512]);
                gll16(Vb + tb + so + c * 512, &V_s[cur ^ 1][ldsb + c * 512]);
            }
        }

        const bool diag = (kt == nt - 1);
        const bool do1  = !(diag && par == 0);   // even-qt diagonal: skip g1
        bfrag_t pfrag[4];

        // ======== g = 0 ========
        {
            f32x16 s;
#pragma unroll
            for (int i = 0; i < 16; ++i) s[i] = 0.f;
            const u16* krow = &K_s[cur][c31 * 128];
#pragma unroll
            for (int ks = 0; ks < 8; ++ks) {
                int slot = (ks * 2 + hi) ^ (c31 & 15);
                bfrag_t kf = *(const bfrag_t*)(krow + slot * 8);
                s = __builtin_amdgcn_mfma_f32_32x32x16_bf16(kf, qf[ks], s, 0, 0, 0);
            }
            if (diag && par == 0) {   // triangular mask: crow > c31
#pragma unroll
                for (int r = 0; r < 16; ++r) {
                    int crow = (r & 3) + 8 * (r >> 2) + 4 * hi;
                    if (crow > c31) s[r] = -1e30f;
                }
            }
#pragma unroll
            for (int r = 0; r < 16; ++r) s[r] = exp2f(s[r]);
            lsum += tsum16(s);
            u32 W[8];
#pragma unroll
            for (int t2 = 0; t2 < 8; ++t2)
                asm("v_cvt_pk_bf16_f32 %0, %1, %2"
                    : "=v"(W[t2]) : "v"(s[2 * t2]), "v"(s[2 * t2 + 1]));
#pragma unroll
            for (int u2 = 0; u2 < 2; ++u2) {
                u32 x0 = W[4 * u2 + 0], y0 = W[4 * u2 + 2];
                u32 x1 = W[4 * u2 + 1], y1 = W[4 * u2 + 3];
                asm("v_permlane32_swap_b32 %0, %1" : "+v"(x0), "+v"(y0));
                asm("v_permlane32_swap_b32 %0, %1" : "+v"(x1), "+v"(y1));
                union { u32 w[4]; bfrag_t f; } cvt;
                cvt.w[0] = x0; cvt.w[1] = x1; cvt.w[2] = y0; cvt.w[3] = y1;
                pfrag[u2] = cvt.f;
            }
        }
        // ======== g = 1 ========
        if (do1) {
            f32x16 s;
#pragma unroll
            for (int i = 0; i < 16; ++i) s[i] = 0.f;
            const u16* krow = &K_s[cur][(32 + c31) * 128];
#pragma unroll
            for (int ks = 0; ks < 8; ++ks) {
                int slot = (ks * 2 + hi) ^ (c31 & 15);
                bfrag_t kf = *(const bfrag_t*)(krow + slot * 8);
                s = __builtin_amdgcn_mfma_f32_32x32x16_bf16(kf, qf[ks], s, 0, 0, 0);
            }
            if (diag) {               // par==1: triangular mask on g1
#pragma unroll
                for (int r = 0; r < 16; ++r) {
                    int crow = (r & 3) + 8 * (r >> 2) + 4 * hi;
                    if (crow > c31) s[r] = -1e30f;
                }
            }
#pragma unroll
            for (int r = 0; r < 16; ++r) s[r] = exp2f(s[r]);
            lsum += tsum16(s);
            u32 W[8];
#pragma unroll
            for (int t2 = 0; t2 < 8; ++t2)
                asm("v_cvt_pk_bf16_f32 %0, %1, %2"
                    : "=v"(W[t2]) : "v"(s[2 * t2]), "v"(s[2 * t2 + 1]));
#pragma unroll
            for (int u2 = 0; u2 < 2; ++u2) {
                u32 x0 = W[4 * u2 + 0], y0 = W[4 * u2 + 2];
                u32 x1 = W[4 * u2 + 1], y1 = W[4 * u2 + 3];
                asm("v_permlane32_swap_b32 %0, %1" : "+v"(x0), "+v"(y0));
                asm("v_permlane32_swap_b32 %0, %1" : "+v"(x1), "+v"(y1));
                union { u32 w[4]; bfrag_t f; } cvt;
                cvt.w[0] = x0; cvt.w[1] = x1; cvt.w[2] = y0; cvt.w[3] = y1;
                pfrag[2 + u2] = cvt.f;
            }
        }

        // ---- O^T += V^T * P^T (V[cur] is stable: prefetch went to [cur^1])
#pragma unroll
        for (int dg = 0; dg < 4; ++dg) {
            const int d  = dg * 32 + c31;
            const int d2 = d >> 1;
            const u16* vrow = &V_s[cur][d2 * 128];
#pragma unroll
            for (int jsl = 0; jsl < 2; ++jsl) {
                int S = ((jsl * 2 + hi) + ((d & 1) << 3)) ^ (d2 & 15);
                bfrag_t vf = *(const bfrag_t*)(vrow + S * 8);
                oacc[dg] = __builtin_amdgcn_mfma_f32_32x32x16_bf16(vf, pfrag[jsl], oacc[dg], 0, 0, 0);
            }
        }
        if (do1) {
#pragma unroll
            for (int dg = 0; dg < 4; ++dg) {
                const int d  = dg * 32 + c31;
                const int d2 = d >> 1;
                const u16* vrow = &V_s[cur][d2 * 128];
#pragma unroll
                for (int jsl = 2; jsl < 4; ++jsl) {
                    int S = ((jsl * 2 + hi) + ((d & 1) << 3)) ^ (d2 & 15);
                    bfrag_t vf = *(const bfrag_t*)(vrow + S * 8);
                    oacc[dg] = __builtin_amdgcn_mfma_f32_32x32x16_bf16(vf, pfrag[jsl], oacc[dg], 0, 0, 0);
                }
            }
        }

        cur ^= 1;
    }

    // ---- epilogue: ONE cross-half reduction completes the denominator
    lsum += __shfl_xor(lsum, 32);
    float inv = 1.f / lsum;
#pragma unroll
    for (int dg = 0; dg < 4; ++dg) {
#pragma unroll
        for (int rq = 0; rq < 4; ++rq) {
            float4 v;
            v.x = oacc[dg][rq * 4 + 0] * inv;
            v.y = oacc[dg][rq * 4 + 1] * inv;
            v.z = oacc[dg][rq * 4 + 2] * inv;
            v.w = oacc[dg][rq * 4 + 3] * inv;
            *(float4*)(og + (rowbase + c31) * HD + dg * 32 + rq * 8 + hi * 4) = v;
        }
    }
}

extern "C" void kernel_launch(void* const* d_in, const int* in_sizes, int n_in,
                              void* d_out, int out_size, void* d_ws, size_t ws_size,
                              hipStream_t stream)
{
    (void)in_sizes; (void)n_in; (void)out_size; (void)ws_size;
    const float* q = (const float*)d_in[0];
    const float* k = (const float*)d_in[1];
    const float* v = (const float*)d_in[2];
    float* o = (float*)d_out;
    u16* wsK = (u16*)d_ws;
    u16* wsV = wsK + (size_t)32 * NTILE * TILE_E;   // 8MB each
    mea_prep<<<dim3(512),  dim3(256), 0, stream>>>(k, v, wsK, wsV);
    // grid: 8 XCD x (32 qt heavy-first x 4 bh); 2 blocks/CU
    mea_main<<<dim3(1024), dim3(256), 0, stream>>>(q, wsK, wsV, o);
}

// Round 10
// 76.979 us; speedup vs baseline: 1.4254x; 1.0363x over previous
//
#include <hip/hip_runtime.h>

// MemoryEfficientAttention: B=2,H=16,S=4096,D=128, CHUNK=1024.
// R10 = R9 structure + complement-paired q-tiles: each block does q-tile
// (31-p) then (p) for p=0..15 -> EXACTLY 17 K-tile iterations per block.
// Grid 512 = 2 blocks/CU: zero dispatch tail, zero imbalance.
// 64KB LDS (K,V both double-buffered), one barrier/tile, no-max softmax,
// diag parity half-skip, pre-swizzled bf16 ws, gll16 DMA.

typedef __attribute__((ext_vector_type(8))) short bfrag_t;   // 8 bf16
typedef __attribute__((ext_vector_type(16))) float f32x16;
typedef unsigned short u16;
typedef unsigned int   u32;

#define SEQ     4096
#define SCHUNK  1024
#define HD      128
#define NTILE   16
#define TILE_E  8192

__device__ __forceinline__ u16 f2bf(float f) {
    union { float f; unsigned u; } x; x.f = f;
    unsigned r = x.u + 0x7fffu + ((x.u >> 16) & 1u);   // RNE
    return (u16)(r >> 16);
}

// ---------------- prep: f32 -> bf16, transpose V, bake LDS swizzle ----------------
// K tile: elem K[j][s*8+e] at j*128 + ((s ^ (j&15))*8) + e          (s=0..15)
// V^T tile: elem V[jo*8+jj][d] at d2*128 + (((jo + 8*(d&1)) ^ (d2&15))*8) + jj, d2=d>>1
__global__ __launch_bounds__(256)
void mea_prep(const float* __restrict__ kg, const float* __restrict__ vg,
              u16* __restrict__ wsK, u16* __restrict__ wsV)
{
    const int tid  = threadIdx.x;
    const int tile = blockIdx.x;            // 512 = 32 bh x 16 kt
    const int bh = tile >> 4, kt = tile & 15;
    const long gsrc = (long)bh * SEQ * HD + (long)kt * 64 * HD;
    const long gdst = (long)tile * TILE_E;

#pragma unroll
    for (int i = 0; i < 4; ++i) {
        int oid = i * 256 + tid;
        int j = oid >> 4, s = oid & 15;
        const float* kp = kg + gsrc + j * HD + s * 8;
        float4 a = *(const float4*)kp;
        float4 b = *(const float4*)(kp + 4);
        bfrag_t f;
        f[0]=f2bf(a.x); f[1]=f2bf(a.y); f[2]=f2bf(a.z); f[3]=f2bf(a.w);
        f[4]=f2bf(b.x); f[5]=f2bf(b.y); f[6]=f2bf(b.z); f[7]=f2bf(b.w);
        *(bfrag_t*)(wsK + gdst + j * 128 + ((s ^ (j & 15)) * 8)) = f;
    }
#pragma unroll
    for (int i = 0; i < 4; ++i) {
        int oid = i * 256 + tid;
        int jo = oid >> 7, d = oid & 127;
        const float* vp = vg + gsrc + jo * 8 * HD + d;
        bfrag_t f;
#pragma unroll
        for (int jj = 0; jj < 8; ++jj) f[jj] = f2bf(vp[jj * HD]);
        int d2 = d >> 1;
        int S  = (jo + ((d & 1) << 3)) ^ (d2 & 15);
        *(bfrag_t*)(wsV + gdst + d2 * 128 + S * 8) = f;
    }
}

__device__ __forceinline__ void gll16(const u16* g, u16* l) {
    __builtin_amdgcn_global_load_lds((const __attribute__((address_space(1))) u32*)g,
                                     (__attribute__((address_space(3))) u32*)l, 16, 0, 0);
}

__device__ __forceinline__ float tsum16(const f32x16& p) {
    float a0 = (p[0] + p[1]) + (p[2] + p[3]);
    float a1 = (p[4] + p[5]) + (p[6] + p[7]);
    float a2 = (p[8] + p[9]) + (p[10] + p[11]);
    float a3 = (p[12] + p[13]) + (p[14] + p[15]);
    return (a0 + a1) + (a2 + a3);
}

// ---------------- main attention kernel ----------------
__global__ __launch_bounds__(256, 2)
void mea_main(const float* __restrict__ qg, const u16* __restrict__ wsK,
              const u16* __restrict__ wsV, float* __restrict__ og)
{
    __shared__ __align__(16) u16 K_s[2][TILE_E];   // 16KB x2
    __shared__ __align__(16) u16 V_s[2][TILE_E];   // 16KB x2

    const int tid  = threadIdx.x;
    const int lane = tid & 63;
    const int wv   = tid >> 6;       // chunk 0..3
    const int c31  = lane & 31;
    const int hi   = lane >> 5;

    // XCD-aware: 4 bh per XCD; complement pair p: q-tiles (31-p) then (p).
    const int x   = blockIdx.x & 7;
    const int idx = blockIdx.x >> 3;          // 0..63
    const int p   = idx >> 2;                 // 0..15
    const int bh  = x * 4 + (idx & 3);

    const long bhrow = (long)bh * SEQ + (long)wv * SCHUNK;
    const u16* Kb = wsK + (long)bh * NTILE * TILE_E;
    const u16* Vb = wsV + (long)bh * NTILE * TILE_E;
    const int so   = wv * 2048 + lane * 8; // wave's global-src slice (u16 elems)
    const int ldsb = wv * 2048;            // wave-uniform LDS dest base
    const float qs = 0.12751723f;          // rsqrt(128) * log2(e)

    // prologue: DMA K(0), V(0) of segment A -> buf0
#pragma unroll
    for (int c = 0; c < 4; ++c) {
        gll16(Kb + so + c * 512, &K_s[0][ldsb + c * 512]);
        gll16(Vb + so + c * 512, &V_s[0][ldsb + c * 512]);
    }

    int cur = 0;
    for (int seg = 0; seg < 2; ++seg) {
        const int qt  = seg ? p : (31 - p);
        const int nt  = (qt >> 1) + 1;     // causal K-tile count
        const int par = qt & 1;            // 0: diag masks g0 (skip g1); 1: masks g1
        const long rowbase = bhrow + (long)qt * 32;

        // ---- Q fragments (B-op: n=q=c31, k=d=ks*16+hi*8+e); fold scale*log2e
        bfrag_t qf[8];
        {
            const float* qp = qg + (rowbase + c31) * HD + hi * 8;
#pragma unroll
            for (int ks = 0; ks < 8; ++ks) {
                float4 a = *(const float4*)(qp + ks * 16);
                float4 b = *(const float4*)(qp + ks * 16 + 4);
                bfrag_t f;
                f[0]=f2bf(a.x*qs); f[1]=f2bf(a.y*qs); f[2]=f2bf(a.z*qs); f[3]=f2bf(a.w*qs);
                f[4]=f2bf(b.x*qs); f[5]=f2bf(b.y*qs); f[6]=f2bf(b.z*qs); f[7]=f2bf(b.w*qs);
                qf[ks] = f;
            }
        }

        f32x16 oacc[4];                // O^T[d][q]: lane=q-col, 16 d-rows per dgrp
#pragma unroll
        for (int d = 0; d < 4; ++d)
#pragma unroll
            for (int i = 0; i < 16; ++i) oacc[d][i] = 0.f;
        float lsum = 0.f;              // this lane's half of the denominator

        for (int kt = 0; kt < nt; ++kt) {
            __syncthreads();   // vmcnt(0): K(kt),V(kt) landed everywhere; bufs ^1 free

            // prefetch: next tile of this segment, or segment B's tile 0 at the seam
            if (kt + 1 < nt) {
                const long tb = (long)(kt + 1) * TILE_E;
#pragma unroll
                for (int c = 0; c < 4; ++c) {
                    gll16(Kb + tb + so + c * 512, &K_s[cur ^ 1][ldsb + c * 512]);
                    gll16(Vb + tb + so + c * 512, &V_s[cur ^ 1][ldsb + c * 512]);
                }
            } else if (seg == 0) {
#pragma unroll
                for (int c = 0; c < 4; ++c) {
                    gll16(Kb + so + c * 512, &K_s[cur ^ 1][ldsb + c * 512]);
                    gll16(Vb + so + c * 512, &V_s[cur ^ 1][ldsb + c * 512]);
                }
            }

            const bool diag = (kt == nt - 1);
            const bool do1  = !(diag && par == 0);   // even-qt diagonal: skip g1
            bfrag_t pfrag[4];

            // ======== g = 0 ========
            {
                f32x16 s;
#pragma unroll
                for (int i = 0; i < 16; ++i) s[i] = 0.f;
                const u16* krow = &K_s[cur][c31 * 128];
#pragma unroll
                for (int ks = 0; ks < 8; ++ks) {
                    int slot = (ks * 2 + hi) ^ (c31 & 15);
                    bfrag_t kf = *(const bfrag_t*)(krow + slot * 8);
                    s = __builtin_amdgcn_mfma_f32_32x32x16_bf16(kf, qf[ks], s, 0, 0, 0);
                }
                if (diag && par == 0) {   // triangular mask: crow > c31
#pragma unroll
                    for (int r = 0; r < 16; ++r) {
                        int crow = (r & 3) + 8 * (r >> 2) + 4 * hi;
                        if (crow > c31) s[r] = -1e30f;
                    }
                }
#pragma unroll
                for (int r = 0; r < 16; ++r) s[r] = exp2f(s[r]);
                lsum += tsum16(s);
                u32 W[8];
#pragma unroll
                for (int t2 = 0; t2 < 8; ++t2)
                    asm("v_cvt_pk_bf16_f32 %0, %1, %2"
                        : "=v"(W[t2]) : "v"(s[2 * t2]), "v"(s[2 * t2 + 1]));
#pragma unroll
                for (int u2 = 0; u2 < 2; ++u2) {
                    u32 x0 = W[4 * u2 + 0], y0 = W[4 * u2 + 2];
                    u32 x1 = W[4 * u2 + 1], y1 = W[4 * u2 + 3];
                    asm("v_permlane32_swap_b32 %0, %1" : "+v"(x0), "+v"(y0));
                    asm("v_permlane32_swap_b32 %0, %1" : "+v"(x1), "+v"(y1));
                    union { u32 w[4]; bfrag_t f; } cvt;
                    cvt.w[0] = x0; cvt.w[1] = x1; cvt.w[2] = y0; cvt.w[3] = y1;
                    pfrag[u2] = cvt.f;
                }
            }
            // ======== g = 1 ========
            if (do1) {
                f32x16 s;
#pragma unroll
                for (int i = 0; i < 16; ++i) s[i] = 0.f;
                const u16* krow = &K_s[cur][(32 + c31) * 128];
#pragma unroll
                for (int ks = 0; ks < 8; ++ks) {
                    int slot = (ks * 2 + hi) ^ (c31 & 15);
                    bfrag_t kf = *(const bfrag_t*)(krow + slot * 8);
                    s = __builtin_amdgcn_mfma_f32_32x32x16_bf16(kf, qf[ks], s, 0, 0, 0);
                }
                if (diag) {               // par==1: triangular mask on g1
#pragma unroll
                    for (int r = 0; r < 16; ++r) {
                        int crow = (r & 3) + 8 * (r >> 2) + 4 * hi;
                        if (crow > c31) s[r] = -1e30f;
                    }
                }
#pragma unroll
                for (int r = 0; r < 16; ++r) s[r] = exp2f(s[r]);
                lsum += tsum16(s);
                u32 W[8];
#pragma unroll
                for (int t2 = 0; t2 < 8; ++t2)
                    asm("v_cvt_pk_bf16_f32 %0, %1, %2"
                        : "=v"(W[t2]) : "v"(s[2 * t2]), "v"(s[2 * t2 + 1]));
#pragma unroll
                for (int u2 = 0; u2 < 2; ++u2) {
                    u32 x0 = W[4 * u2 + 0], y0 = W[4 * u2 + 2];
                    u32 x1 = W[4 * u2 + 1], y1 = W[4 * u2 + 3];
                    asm("v_permlane32_swap_b32 %0, %1" : "+v"(x0), "+v"(y0));
                    asm("v_permlane32_swap_b32 %0, %1" : "+v"(x1), "+v"(y1));
                    union { u32 w[4]; bfrag_t f; } cvt;
                    cvt.w[0] = x0; cvt.w[1] = x1; cvt.w[2] = y0; cvt.w[3] = y1;
                    pfrag[2 + u2] = cvt.f;
                }
            }

            // ---- O^T += V^T * P^T (V[cur] stable: prefetch went to [cur^1])
#pragma unroll
            for (int dg = 0; dg < 4; ++dg) {
                const int d  = dg * 32 + c31;
                const int d2 = d >> 1;
                const u16* vrow = &V_s[cur][d2 * 128];
#pragma unroll
                for (int jsl = 0; jsl < 2; ++jsl) {
                    int S = ((jsl * 2 + hi) + ((d & 1) << 3)) ^ (d2 & 15);
                    bfrag_t vf = *(const bfrag_t*)(vrow + S * 8);
                    oacc[dg] = __builtin_amdgcn_mfma_f32_32x32x16_bf16(vf, pfrag[jsl], oacc[dg], 0, 0, 0);
                }
            }
            if (do1) {
#pragma unroll
                for (int dg = 0; dg < 4; ++dg) {
                    const int d  = dg * 32 + c31;
                    const int d2 = d >> 1;
                    const u16* vrow = &V_s[cur][d2 * 128];
#pragma unroll
                    for (int jsl = 2; jsl < 4; ++jsl) {
                        int S = ((jsl * 2 + hi) + ((d & 1) << 3)) ^ (d2 & 15);
                        bfrag_t vf = *(const bfrag_t*)(vrow + S * 8);
                        oacc[dg] = __builtin_amdgcn_mfma_f32_32x32x16_bf16(vf, pfrag[jsl], oacc[dg], 0, 0, 0);
                    }
                }
            }

            cur ^= 1;
        }

        // ---- per-segment epilogue: cross-half lsum, divide, store
        lsum += __shfl_xor(lsum, 32);
        float inv = 1.f / lsum;
#pragma unroll
        for (int dg = 0; dg < 4; ++dg) {
#pragma unroll
            for (int rq = 0; rq < 4; ++rq) {
                float4 v;
                v.x = oacc[dg][rq * 4 + 0] * inv;
                v.y = oacc[dg][rq * 4 + 1] * inv;
                v.z = oacc[dg][rq * 4 + 2] * inv;
                v.w = oacc[dg][rq * 4 + 3] * inv;
                *(float4*)(og + (rowbase + c31) * HD + dg * 32 + rq * 8 + hi * 4) = v;
            }
        }
    }
}

extern "C" void kernel_launch(void* const* d_in, const int* in_sizes, int n_in,
                              void* d_out, int out_size, void* d_ws, size_t ws_size,
                              hipStream_t stream)
{
    (void)in_sizes; (void)n_in; (void)out_size; (void)ws_size;
    const float* q = (const float*)d_in[0];
    const float* k = (const float*)d_in[1];
    const float* v = (const float*)d_in[2];
    float* o = (float*)d_out;
    u16* wsK = (u16*)d_ws;
    u16* wsV = wsK + (size_t)32 * NTILE * TILE_E;   // 8MB each
    mea_prep<<<dim3(512), dim3(256), 0, stream>>>(k, v, wsK, wsV);
    // grid: 512 blocks = 2/CU exactly; every block = 17 K-tile iterations
    mea_main<<<dim3(512), dim3(256), 0, stream>>>(q, wsK, wsV, o);
}